// Round 1
// 329.987 us; speedup vs baseline: 1.0698x; 1.0698x over previous
//
#include <hip/hip_runtime.h>

// Problem constants (from reference):
//   B=1024 batches, S=200 seq, D=64 dim, C=256 clusters
// Outputs (concat in d_out, all read back as float32):
//   out[0] cluster_emb  [B,C,D] = 16,777,216 f32
//   out[1] cluster_mask [B,C,S] = 52,428,800 f32 (0.0/1.0 values)
//
// Structure: role-split blocks, 3 blocks per batch.
//   role 0,1: stream one half of cluster_mask[b] each (pure store-bound,
//             800 B LDS, nontemporal vec4 stores).
//   role 2:   compute cluster_emb[b] via a tiny counting-sort CSR and
//             register accumulation (lane = d, cluster wave-uniform).
// LDS ~4.7 KB -> 8 blocks/CU resident; store-bound and latency-bound
// blocks co-reside and overlap, unlike the old 64KB-LDS 2-block/CU design.
#define NB 1024
#define NS 200
#define ND 64
#define NC 256

typedef float v4f __attribute__((ext_vector_type(4)));

__global__ __launch_bounds__(256, 8) void s3rec_cluster_kernel(
    const float* __restrict__ x,       // [B,S,D]
    const int*   __restrict__ labels,  // [B,S]
    const int*   __restrict__ amask,   // [B,S]
    float* __restrict__ out_emb,       // [B,C,D]
    float* __restrict__ out_mask)      // [B,C,S]
{
    __shared__ __align__(16) int s_lab[NS];  // label if masked else -1
    __shared__ int   s_cnt[NC];
    __shared__ int   s_off[NC];
    __shared__ float s_inv[NC];
    __shared__ int   s_list[NS];             // seq indices grouped by cluster
    __shared__ int   s_part[4];              // per-wave scan partials

    const int role = blockIdx.x % 3;   // 0,1 = mask halves; 2 = emb
    const int b    = blockIdx.x / 3;
    const int t    = threadIdx.x;

    // --- stage labels packed with mask (one iter: t<200) ---
    for (int i = t; i < NS; i += 256) {
        const int l = labels[b * NS + i];
        const int m = amask [b * NS + i];
        s_lab[i] = (m != 0) ? l : -1;
    }

    if (role < 2) {
        // ---------------- mask writer: half of [C,S] = 6400 vec4 ----------
        __syncthreads();
        v4f* om4 = reinterpret_cast<v4f*>(out_mask + (size_t)b * (NC * NS));
        const int i4lo = role * 6400;
        #pragma unroll 5
        for (int k = 0; k < 25; ++k) {
            const int i4 = i4lo + k * 256 + t;
            const int c  = i4 / 50;               // magic-mul
            const int s0 = (i4 - c * 50) * 4;     // multiple of 4 -> 16B aligned
            const int4 lv = *reinterpret_cast<const int4*>(&s_lab[s0]);
            v4f v;
            v.x = (lv.x == c) ? 1.0f : 0.0f;
            v.y = (lv.y == c) ? 1.0f : 0.0f;
            v.z = (lv.z == c) ? 1.0f : 0.0f;
            v.w = (lv.w == c) ? 1.0f : 0.0f;
            __builtin_nontemporal_store(v, &om4[i4]);
        }
        return;
    }

    // ---------------- emb computer ---------------------------------------
    // 1) histogram (t indexes clusters exactly: NC == 256)
    s_cnt[t] = 0;
    __syncthreads();
    if (t < NS) {
        const int l = s_lab[t];
        if (l >= 0) atomicAdd(&s_cnt[l], 1);
    }
    __syncthreads();

    // 2) inverse counts + exclusive prefix scan over 256 counts
    const int lane = t & 63;
    const int w    = t >> 6;
    const int cnt  = s_cnt[t];
    s_inv[t] = (cnt > 0) ? (1.0f / (float)cnt) : 0.0f;

    int v = cnt;                                  // wave-inclusive scan
    #pragma unroll
    for (int d = 1; d < 64; d <<= 1) {
        const int n = __shfl_up(v, d, 64);
        if (lane >= d) v += n;
    }
    if (lane == 63) s_part[w] = v;                // wave totals
    __syncthreads();
    int base = 0;
    for (int i = 0; i < w; ++i) base += s_part[i];
    s_off[t] = base + v - cnt;                    // exclusive offset
    __syncthreads();

    // 3) deterministic scatter: rank = #earlier entries with same label,
    //    so each cluster's list is ascending in s (matches reference's
    //    left-to-right reduction order).
    if (t < NS) {
        const int L = s_lab[t];
        if (L >= 0) {
            int r = 0;
            for (int s2 = 0; s2 < t; ++s2) r += (s_lab[s2] == L) ? 1 : 0;
            s_list[s_off[L] + r] = t;
        }
    }
    __syncthreads();

    // 4) accumulate per cluster in a register (lane = d, c wave-uniform)
    //    and write every row (zeros included) -> full [C,D] coverage.
    const float* xb = x + (size_t)b * NS * ND;
    float* oe = out_emb + (size_t)b * (NC * ND);
    const int cend = w * 64 + 64;
    for (int c = w * 64; c < cend; ++c) {
        const int n = s_cnt[c];
        const int o = s_off[c];
        float acc = 0.0f;
        for (int j = 0; j < n; ++j) {
            const int s = s_list[o + j];
            acc += xb[s * ND + lane];             // 256B coalesced, s uniform
        }
        __builtin_nontemporal_store(acc * s_inv[c], &oe[c * ND + lane]);
    }
}

extern "C" void kernel_launch(void* const* d_in, const int* in_sizes, int n_in,
                              void* d_out, int out_size, void* d_ws, size_t ws_size,
                              hipStream_t stream) {
    const float* x      = (const float*)d_in[0];  // [B,S,D] f32
    const int*   labels = (const int*)  d_in[1];  // [B,S]   i32
    const int*   amask  = (const int*)  d_in[2];  // [B,S]   i32

    float* out_emb  = (float*)d_out;                          // [B,C,D]
    float* out_mask = out_emb + (size_t)NB * NC * ND;         // [B,C,S]

    s3rec_cluster_kernel<<<dim3(NB * 3), dim3(256), 0, stream>>>(
        x, labels, amask, out_emb, out_mask);
}